// Round 3
// baseline (601.683 us; speedup 1.0000x reference)
//
#include <hip/hip_runtime.h>

typedef unsigned short u16;
using short8  = __attribute__((ext_vector_type(8))) short;
using floatx4 = __attribute__((ext_vector_type(4))) float;
using half_t  = _Float16;
using half2_t = __attribute__((ext_vector_type(2))) _Float16;

constexpr int B_ = 256, T_ = 256, I_ = 16, H_ = 256, O_ = 11;
constexpr int HYP = 512;
constexpr int N1_ = H_ * I_ + H_ * H_ + 2 * H_;   // 70144
constexpr int N2_ = O_ * H_ + O_;                 // 2827
constexpr int GN  = N1_ + N2_;                    // 72971

// d_out is float32; offsets in float elements
constexpr size_t OUT_ACT  = 0;
constexpr size_t OUT_BLDI = (size_t)B_ * T_ * 3;            // 196608
constexpr size_t OUT_H    = OUT_BLDI + (size_t)B_ * T_ * 8; // 720896
constexpr size_t OUT_P1   = OUT_H + (size_t)B_ * H_;        // 786432
constexpr size_t OUT_P2   = OUT_P1 + (size_t)B_ * N1_;      // 18743296

__device__ inline float bf2f(u16 u) {
    union { unsigned int i; float f; } v; v.i = ((unsigned int)u) << 16; return v.f;
}
__device__ inline u16 f2bf(float f) {
    unsigned int x = __float_as_uint(f);
    unsigned int r = (x + 0x7fffu + ((x >> 16) & 1u)) >> 16;   // RNE, finite inputs
    return (u16)r;
}
__device__ inline float fdot2(half2_t a, half2_t b, float c) {
#if __has_builtin(__builtin_amdgcn_fdot2)
    return __builtin_amdgcn_fdot2(a, b, c, false);
#else
    return c + (float)a.x * (float)b.x + (float)a.y * (float)b.y;
#endif
}

// Per-tensor dtype sniff (wave-uniform). Even-indexed u16s of genuine bf16 data
// have exponents in a narrow band (~64/64 in-band); fp32 low mantissa halves are
// uniform 16-bit noise (~16/64 in-band). Zero tensors read 0.0 under either verdict.
__device__ inline bool sniff_f32(const void* p) {
    const u16* w = (const u16*)p;
    const int lane = threadIdx.x & 63;
    u16 u = w[lane * 2];
    unsigned e = (u >> 7) & 0xFF;
    bool inband = (u == 0) || (e >= 77 && e <= 140);
    return __popcll(__ballot(inband)) < 56;
}

__device__ inline float ldr(const void* p, size_t i, bool f32) {
    return f32 ? ((const float*)p)[i] : bf2f(((const u16*)p)[i]);
}

// ---------------- kernel 1: h1 = relu(bld @ W1 + b1) -> bf16 stash in out[0..131072) -------
// (act region floats [0,196608) are fully rewritten by the RNN kernel afterwards)
__global__ void h1_kernel(const void* __restrict__ bld, const void* __restrict__ W1,
                          const void* __restrict__ b1, u16* __restrict__ h1) {
    const bool bldf = sniff_f32(bld);
    const bool w1f  = sniff_f32(W1);
    const bool b1f  = sniff_f32(b1);
    const int b = blockIdx.x;
    const int j = threadIdx.x;
    float acc = ldr(b1, j, b1f);
#pragma unroll
    for (int k = 0; k < 8; k++)
        acc += ldr(bld, b * 8 + k, bldf) * ldr(W1, k * HYP + j, w1f);
    h1[b * HYP + j] = f2bf(fmaxf(acc, 0.f));
}

// ---------------- kernel 2: flat = h1 @ W2 + b2 -> params1/params2 (f32, d_out) ------------
template<bool W2F32>
__device__ void gemm_body(const u16* __restrict__ A, const void* __restrict__ Bm,
                          const void* __restrict__ b2, bool b2f,
                          float* __restrict__ out) {
    const int nb   = blockIdx.x * 64;
    const int lane = threadIdx.x & 63;
    const int wid  = threadIdx.x >> 6;
    const int l15  = lane & 15;
    const int q    = lane >> 4;

    int  col[4]; bool cv[4];
#pragma unroll
    for (int j = 0; j < 4; j++) {
        int c = nb + j * 16 + l15;
        cv[j]  = (c < GN);
        col[j] = cv[j] ? c : (GN - 1);
    }

    const u16* ap[4];
#pragma unroll
    for (int i = 0; i < 4; i++)
        ap[i] = A + (wid * 64 + i * 16 + l15) * HYP + q * 8;

    floatx4 acc[4][4] = {};

#pragma unroll 4
    for (int ks = 0; ks < 16; ks++) {
        short8 af[4];
#pragma unroll
        for (int i = 0; i < 4; i++)
            af[i] = *(const short8*)(ap[i] + ks * 32);

        short8 bfr[4];
        const size_t rb = (size_t)(ks * 32 + q * 8) * (size_t)GN;
#pragma unroll
        for (int t = 0; t < 8; t++) {
            const size_t ro = rb + (size_t)t * (size_t)GN;
#pragma unroll
            for (int j = 0; j < 4; j++) {
                if constexpr (W2F32)
                    bfr[j][t] = (short)f2bf(((const float*)Bm)[ro + (size_t)col[j]]);
                else
                    bfr[j][t] = (short)((const u16*)Bm)[ro + (size_t)col[j]];
            }
        }
#pragma unroll
        for (int i = 0; i < 4; i++)
#pragma unroll
            for (int j = 0; j < 4; j++)
                acc[i][j] = __builtin_amdgcn_mfma_f32_16x16x32_bf16(af[i], bfr[j], acc[i][j], 0, 0, 0);
    }

    const bool isP2 = (nb >= N1_);   // N1_ multiple of 64 -> no straddle
#pragma unroll
    for (int j = 0; j < 4; j++) {
        const float bias = ldr(b2, col[j], b2f);
#pragma unroll
        for (int i = 0; i < 4; i++) {
            const int mbase = wid * 64 + i * 16 + q * 4;
#pragma unroll
            for (int r = 0; r < 4; r++) {
                if (cv[j]) {
                    const float v = acc[i][j][r] + bias;
                    const int m = mbase + r;
                    size_t dst;
                    if (isP2) dst = OUT_P2 + (size_t)m * N2_ + (size_t)(col[j] - N1_);
                    else      dst = OUT_P1 + (size_t)m * N1_ + (size_t)col[j];
                    out[dst] = v;
                }
            }
        }
    }
}
__global__ __launch_bounds__(256) void gemm_kernel(const u16* A, const void* Bm,
                                                   const void* b2, float* out) {
    const bool w2f = sniff_f32(Bm);
    const bool b2f = sniff_f32(b2);
    if (w2f) gemm_body<true>(A, Bm, b2, b2f, out);
    else     gemm_body<false>(A, Bm, b2, b2f, out);
}

// ---------------- kernel 3: per-batch RNN scan, fused x_proj + output projection -----------
// 1 block per batch. 512 thr: tid = hh*256 + g. Thread holds W_hh[g][hh*128..+127] as 64 half2.
__global__ __launch_bounds__(512) void rnn_kernel(const void* __restrict__ stim,
                                                  float* __restrict__ out) {
    const bool stf = sniff_f32(stim);
    const int b   = blockIdx.x;
    const int tid = threadIdx.x;
    const int g   = tid & 255;
    const int hh  = tid >> 8;

    const float* p1 = out + OUT_P1 + (size_t)b * N1_;
    const float* p2 = out + OUT_P2 + (size_t)b * N2_;

    __shared__ half2_t hbuf[2][128];     // h as 256 halfs, double-buffered
    __shared__ float   pbuf[2][256];     // matvec partials
    __shared__ half2_t stim_s[T_ * 8];   // stimulus[b] as half2 (256 t x 16 i)

    // stage stimulus -> half2
    if (stf) {
        const float2* sp = (const float2*)stim + (size_t)b * T_ * 8;
        for (int idx = tid; idx < T_ * 8; idx += 512) {
            float2 v = sp[idx];
            half2_t h; h.x = (half_t)v.x; h.y = (half_t)v.y;
            stim_s[idx] = h;
        }
    } else {
        const unsigned int* sp = (const unsigned int*)((const u16*)stim + (size_t)b * T_ * I_);
        for (int idx = tid; idx < T_ * 8; idx += 512) {
            unsigned int u = sp[idx];
            union { unsigned int i; float f; } lo, hi;
            lo.i = u << 16; hi.i = u & 0xffff0000u;
            half2_t h; h.x = (half_t)lo.f; h.y = (half_t)hi.f;
            stim_s[idx] = h;
        }
    }

    // W_hh half-row -> registers (params f32, written by gemm; float4-aligned)
    half2_t Wr[64];
    {
        const float4* wp4 = (const float4*)(p1 + H_ * I_ + (size_t)g * H_ + hh * 128);
#pragma unroll
        for (int v = 0; v < 32; v++) {
            float4 r4 = wp4[v];
            half2_t h01, h23;
            h01.x = (half_t)r4.x; h01.y = (half_t)r4.y;
            h23.x = (half_t)r4.z; h23.y = (half_t)r4.w;
            Wr[v * 2 + 0] = h01;
            Wr[v * 2 + 1] = h23;
        }
    }

    // W_ih row + combined bias (hh==1 threads handle the stimulus projection)
    half2_t Wih[8];
    float bc = 0.f;
    if (hh) {
        const float4* ip = (const float4*)(p1 + (size_t)g * I_);
#pragma unroll
        for (int v = 0; v < 4; v++) {
            float4 r4 = ip[v];
            half2_t h01, h23;
            h01.x = (half_t)r4.x; h01.y = (half_t)r4.y;
            h23.x = (half_t)r4.z; h23.y = (half_t)r4.w;
            Wih[v * 2 + 0] = h01;
            Wih[v * 2 + 1] = h23;
        }
        bc = p1[H_ * I_ + H_ * H_ + g] + p1[H_ * I_ + H_ * H_ + H_ + g];
    }

    // W_out chunk (threads 0..175: o = tid>>4, c = tid&15); p2 only 4B-aligned -> scalar
    half2_t Wo[8];
    float bo = 0.f;
    const int oo = tid >> 4, cc = tid & 15;
    if (tid < 176) {
        const float* wop = p2 + oo * H_ + cc * 16;
#pragma unroll
        for (int v = 0; v < 8; v++) {
            half2_t w;
            w.x = (half_t)wop[2 * v];
            w.y = (half_t)wop[2 * v + 1];
            Wo[v] = w;
        }
        bo = p2[O_ * H_ + oo];
    }

    // h0 = 0
    if (tid < 128) {
        half2_t z; z.x = (half_t)0.f; z.y = (half_t)0.f;
        hbuf[0][tid] = z;
    }
    __syncthreads();

    const size_t act_base  = OUT_ACT  + (size_t)b * T_ * 3;
    const size_t bldi_base = OUT_BLDI + (size_t)b * T_ * 8;

    for (int t = 0; t < T_; t++) {
        const int cur = t & 1, nxt = cur ^ 1;

        // half-row matvec partial: W_hh[g][hh*128..] . h[hh*128..]
        const half2_t* hv = &hbuf[cur][hh * 64];
        float a0 = 0.f, a1 = 0.f, a2 = 0.f, a3 = 0.f;
#pragma unroll
        for (int jj = 0; jj < 64; jj += 4) {
            a0 = fdot2(Wr[jj + 0], hv[jj + 0], a0);
            a1 = fdot2(Wr[jj + 1], hv[jj + 1], a1);
            a2 = fdot2(Wr[jj + 2], hv[jj + 2], a2);
            a3 = fdot2(Wr[jj + 3], hv[jj + 3], a3);
        }
        float part = (a0 + a1) + (a2 + a3);

        if (hh) {   // fused x_proj + biases
            float xa = bc;
            if (t > 0) {
                const half2_t* sv = &stim_s[(t - 1) * 8];
#pragma unroll
                for (int i2 = 0; i2 < 8; i2++) xa = fdot2(Wih[i2], sv[i2], xa);
            }
            part += xa;
        }
        pbuf[hh][g] = part;
        __syncthreads();

        if (tid < 256) {
            const float s = pbuf[0][g] + pbuf[1][g];
            const float e = __expf(2.f * s);
            const float hn = 1.f - 2.f / (e + 1.f);   // tanh(s)
            ((half_t*)hbuf[nxt])[g] = (half_t)hn;
            if (t == T_ - 1) out[OUT_H + (size_t)b * H_ + g] = hn;
        }
        __syncthreads();

        // fused output projection: out2[t][o] = W_out[o] . h_t + b_out[o]
        if (tid < 176) {
            const half2_t* h2v = &hbuf[nxt][cc * 8];
            float oa = 0.f;
#pragma unroll
            for (int v = 0; v < 8; v++) oa = fdot2(Wo[v], h2v[v], oa);
            oa += __shfl_xor(oa, 1);
            oa += __shfl_xor(oa, 2);
            oa += __shfl_xor(oa, 4);
            oa += __shfl_xor(oa, 8);
            if (cc == 0) {
                float v2 = oa + bo;
                if (oo < 3) {
                    v2 = 1.f / (1.f + __expf(-v2));
                    out[act_base + (size_t)t * 3 + oo] = v2;
                } else {
                    out[bldi_base + (size_t)t * 8 + (oo - 3)] = v2;
                }
            }
        }
    }
}

extern "C" void kernel_launch(void* const* d_in, const int* in_sizes, int n_in,
                              void* d_out, int out_size, void* d_ws, size_t ws_size,
                              hipStream_t stream) {
    (void)in_sizes; (void)n_in; (void)out_size; (void)d_ws; (void)ws_size;
    const void* bld  = d_in[0];
    const void* stim = d_in[1];
    const void* W1   = d_in[2];
    const void* b1   = d_in[3];
    const void* W2   = d_in[4];
    const void* b2   = d_in[5];
    float* out = (float*)d_out;
    u16* h1 = (u16*)out;   // 256x512 bf16 stash inside act region (rewritten by rnn)

    h1_kernel<<<B_, HYP, 0, stream>>>(bld, W1, b1, h1);
    gemm_kernel<<<(GN + 63) / 64, 256, 0, stream>>>(h1, W2, b2, out);
    rnn_kernel<<<B_, 512, 0, stream>>>(stim, out);
}